// Round 6
// baseline (271.463 us; speedup 1.0000x reference)
//
#include <hip/hip_runtime.h>
#include <math.h>
#include <stdint.h>

// out_i = clamp(out_{i-1}; a_i, a_i+1), a_i = x_i * k.  Clamps compose ->
// associative scan.  SINGLE-PASS, single dispatch:
//  - atomic ticket => block ids in scheduling order (forward-progress safe)
//  - every block publishes its aggregate BEFORE any waiting
//  - wave-parallel FORWARD lookback: wave 0 polls 64 predecessor aggregates
//    per round (ballot), composes via ordered shfl reduce, <=16 rounds.
//    R3's 1600us failure was the serial 1-at-a-time backward walk; this
//    removes that serial chain with no data-distribution assumption.
//  - x read once (registers), out written once: ~67 MB total HBM traffic.

#define TPB 256
#define SEGS 8
#define WAVES (TPB / 64)
#define ELEMS (TPB * SEGS * 4)   // 8192 floats per block -> 1024 blocks @ T=2^23

__device__ __forceinline__ float clampf(float x, float lo, float hi) {
    return fminf(fmaxf(x, lo), hi);
}

// 64-bit word = (flag<<32) | float_bits : self-contained atomic publish/poll
__device__ __forceinline__ void publish(uint64_t* p, float val) {
    uint64_t w = (1ull << 32) | (uint64_t)__float_as_uint(val);
    __hip_atomic_store(p, w, __ATOMIC_RELEASE, __HIP_MEMORY_SCOPE_AGENT);
}
__device__ __forceinline__ bool poll(uint64_t* p, float* val) {
    uint64_t w = __hip_atomic_load(p, __ATOMIC_ACQUIRE, __HIP_MEMORY_SCOPE_AGENT);
    if ((w >> 32) == 0) return false;
    *val = __uint_as_float((uint32_t)w);
    return true;
}

__global__ __launch_bounds__(TPB) void phi_scan(
    const float4* __restrict__ x4,
    const float* __restrict__ kern,
    const float* __restrict__ state,
    float* __restrict__ out,          // T outputs + 1 new_state
    uint32_t* __restrict__ counter,
    uint64_t* __restrict__ aggLo,
    uint64_t* __restrict__ aggHi,
    int nblocks)
{
    __shared__ int s_ticket;
    __shared__ float wtlo[SEGS][WAVES], wthi[SEGS][WAVES];
    __shared__ float s_vb;

    const int t = threadIdx.x, lane = t & 63, w = t >> 6;
    if (t == 0) s_ticket = (int)atomicAdd(counter, 1u);
    __syncthreads();
    const int b = s_ticket;

    const float k = kern[0];
    const size_t base4 = (size_t)b * (TPB * SEGS);

    float a[SEGS][4];               // inputs*k, kept in registers (read x ONCE)
    float eslo[SEGS], eshi[SEGS];   // thread-exclusive within segment
    float Slo[SEGS], Shi[SEGS];     // segment totals

    // ---- block-local scans (structure proven in R3/R5: absmax 0.0) ----
#pragma unroll
    for (int s = 0; s < SEGS; ++s) {
        float4 v = x4[base4 + (size_t)s * TPB + t];   // coalesced
        a[s][0] = v.x * k; a[s][1] = v.y * k; a[s][2] = v.z * k; a[s][3] = v.w * k;
        float lo = a[s][0], hi = a[s][0] + 1.0f;
#pragma unroll
        for (int c = 1; c < 4; ++c) {
            lo = clampf(lo, a[s][c], a[s][c] + 1.0f);
            hi = clampf(hi, a[s][c], a[s][c] + 1.0f);
        }
        // wave inclusive scan (prefix FIRST, self SECOND)
#pragma unroll
        for (int off = 1; off < 64; off <<= 1) {
            float plo = __shfl_up(lo, off);
            float phi_ = __shfl_up(hi, off);
            if (lane >= off) {
                float nlo = clampf(plo, lo, hi);
                float nhi = clampf(phi_, lo, hi);
                lo = nlo; hi = nhi;
            }
        }
        float elo = __shfl_up(lo, 1), ehi = __shfl_up(hi, 1);
        if (lane == 0) { elo = -INFINITY; ehi = INFINITY; }
        eslo[s] = elo; eshi[s] = ehi;
        if (lane == 63) { wtlo[s][w] = lo; wthi[s][w] = hi; }
    }
    __syncthreads();

#pragma unroll
    for (int s = 0; s < SEGS; ++s) {
        float welo = -INFINITY, wehi = INFINITY;      // earlier waves' totals
        for (int i = 0; i < w; ++i) {
            welo = clampf(welo, wtlo[s][i], wthi[s][i]);
            wehi = clampf(wehi, wtlo[s][i], wthi[s][i]);
        }
        float llo = eslo[s], lhi = eshi[s];
        eslo[s] = clampf(welo, llo, lhi);             // compose(waves-before, lanes-before)
        eshi[s] = clampf(wehi, llo, lhi);
        float stl = -INFINITY, sth = INFINITY;        // segment total
#pragma unroll
        for (int i = 0; i < WAVES; ++i) {
            stl = clampf(stl, wtlo[s][i], wthi[s][i]);
            sth = clampf(sth, wtlo[s][i], wthi[s][i]);
        }
        Slo[s] = stl; Shi[s] = sth;
    }

    // ---- publish own aggregate FIRST (unconditional; enables others) ----
    if (t == 0) {
        float Alo = -INFINITY, Ahi = INFINITY;
#pragma unroll
        for (int s = 0; s < SEGS; ++s) {
            Alo = clampf(Alo, Slo[s], Shi[s]);
            Ahi = clampf(Ahi, Slo[s], Shi[s]);
        }
        publish(&aggLo[b], Alo);
        publish(&aggHi[b], Ahi);
    }

    // ---- wave-parallel FORWARD lookback (wave 0) ----
    if (w == 0) {
        float v = state[0];
        const int rounds = (b + 63) >> 6;
        for (int r = 0; r < rounds; ++r) {
            const int j = (r << 6) + lane;
            const bool need = (j < b);
            float alo = -INFINITY, ahi = INFINITY;
            for (;;) {
                bool ready = true;
                if (need) {
                    float l, h;
                    ready = poll(&aggLo[j], &l) && poll(&aggHi[j], &h);
                    if (ready) { alo = l; ahi = h; }
                }
                if (__ballot(ready) == ~0ull) break;
                __builtin_amdgcn_s_sleep(1);
            }
            // ordered reduce: self (earlier j) FIRST, lane+off SECOND.
            // OOB shfl returns self; self-compose of a clamp pair = identity.
            float lo = alo, hi = ahi;
#pragma unroll
            for (int off = 1; off < 64; off <<= 1) {
                float plo = __shfl_down(lo, off);
                float phi_ = __shfl_down(hi, off);
                float nlo = clampf(lo, plo, phi_);
                float nhi = clampf(hi, plo, phi_);
                lo = nlo; hi = nhi;
            }
            float clo = __shfl(lo, 0), chi = __shfl(hi, 0);  // chunk function
            v = clampf(v, clo, chi);                          // apply in order
        }
        if (lane == 0) s_vb = v;
    }
    __syncthreads();

    // ---- apply + write (coalesced; x already in registers) ----
    float p = s_vb;
    float4* out4 = (float4*)out;
#pragma unroll
    for (int s = 0; s < SEGS; ++s) {
        float wv = clampf(p, eslo[s], eshi[s]);       // thread entry in segment
        float4 r;
        wv = clampf(wv, a[s][0], a[s][0] + 1.0f); r.x = wv;
        wv = clampf(wv, a[s][1], a[s][1] + 1.0f); r.y = wv;
        wv = clampf(wv, a[s][2], a[s][2] + 1.0f); r.z = wv;
        wv = clampf(wv, a[s][3], a[s][3] + 1.0f); r.w = wv;
        out4[base4 + (size_t)s * TPB + t] = r;
        p = clampf(p, Slo[s], Shi[s]);                // advance past segment
    }

    if (b == nblocks - 1 && t == 0) {
        float q = s_vb;
#pragma unroll
        for (int s = 0; s < SEGS; ++s) q = clampf(q, Slo[s], Shi[s]);
        out[(size_t)nblocks * ELEMS] = q;             // new_state = last output
    }
}

extern "C" void kernel_launch(void* const* d_in, const int* in_sizes, int n_in,
                              void* d_out, int out_size, void* d_ws, size_t ws_size,
                              hipStream_t stream) {
    const float4* x4   = (const float4*)d_in[0];   // [1,T]
    const float* state = (const float*)d_in[1];    // [1,1]
    const float* kern  = (const float*)d_in[2];    // [1,1]
    float* out = (float*)d_out;                    // T outputs + 1 new_state

    const size_t T = (size_t)in_sizes[0];
    const int nblocks = (int)(T / ELEMS);          // 1024 for T=2^23

    uint32_t* counter = (uint32_t*)d_ws;
    uint64_t* aggLo = (uint64_t*)((char*)d_ws + 16);
    uint64_t* aggHi = aggLo + nblocks;
    const size_t ctl_bytes = 16 + 2 * (size_t)nblocks * sizeof(uint64_t);

    hipMemsetAsync(d_ws, 0, ctl_bytes, stream);    // zero ticket + flags (ws is 0xAA)
    phi_scan<<<nblocks, TPB, 0, stream>>>(x4, kern, state, out,
                                          counter, aggLo, aggHi, nblocks);
}

// Round 7
// 100.621 us; speedup vs baseline: 2.6979x; 2.6979x over previous
//
#include <hip/hip_runtime.h>
#include <math.h>

// out_i = clamp(out_{i-1}; a_i, a_i+1), a_i = x_i * k.  Clamp functions
// p -> min(max(p,lo),hi) compose associatively -> parallel scan.
//
// R6 lesson: any polling/spin design self-poisons via L2 atomic interference.
// Deterministic 2-dispatch structure (R5, absmax 0.0) kept; this round cuts
// the cross-lane overhead: thread owns 32 CONTIGUOUS elements -> serial
// register scan; only ONE 6-step wave shfl pass per kernel (12 bpermutes,
// was 96). Per-thread-contiguous global access is L1-absorbed (each wave's
// 8KB window fully consumed over the 8-iter unroll).

#define TPB 256
#define WAVES (TPB / 64)
#define PT 32                     // floats per thread (contiguous)
#define ELEMS (TPB * PT)          // 8192 floats per block -> 1024 blocks @ 2^23

__device__ __forceinline__ float clampf(float x, float lo, float hi) {
    return fminf(fmaxf(x, lo), hi);
}

// ---------------- K1: per-block composed clamp aggregate ----------------
__global__ __launch_bounds__(TPB) void k_agg(const float4* __restrict__ x4,
                                             const float* __restrict__ kern,
                                             float2* __restrict__ agg) {
    __shared__ float wl[WAVES], wh[WAVES];
    const int t = threadIdx.x, lane = t & 63, w = t >> 6;
    const int b = blockIdx.x;
    const float k = kern[0];

    const float4* p = x4 + (size_t)b * (ELEMS / 4) + (size_t)t * (PT / 4);
    float lo = -INFINITY, hi = INFINITY;
#pragma unroll
    for (int i = 0; i < PT / 4; ++i) {
        float4 v = p[i];
        float a;
        a = v.x * k; lo = clampf(lo, a, a + 1.0f); hi = clampf(hi, a, a + 1.0f);
        a = v.y * k; lo = clampf(lo, a, a + 1.0f); hi = clampf(hi, a, a + 1.0f);
        a = v.z * k; lo = clampf(lo, a, a + 1.0f); hi = clampf(hi, a, a + 1.0f);
        a = v.w * k; lo = clampf(lo, a, a + 1.0f); hi = clampf(hi, a, a + 1.0f);
    }
    // ordered wave reduce: self (earlier) FIRST, lane+off (later) SECOND.
    // OOB shfl returns self; self-compose of a clamp pair is identity.
#pragma unroll
    for (int off = 1; off < 64; off <<= 1) {
        float plo = __shfl_down(lo, off);
        float phi_ = __shfl_down(hi, off);
        float nlo = clampf(lo, plo, phi_);
        float nhi = clampf(hi, plo, phi_);
        lo = nlo; hi = nhi;
    }
    if (lane == 0) { wl[w] = lo; wh[w] = hi; }
    __syncthreads();
    if (t == 0) {
        float L = wl[0], H = wh[0];
#pragma unroll
        for (int i = 1; i < WAVES; ++i) {
            L = clampf(L, wl[i], wh[i]);
            H = clampf(H, wl[i], wh[i]);
        }
        agg[b] = make_float2(L, H);
    }
}

// ------- K2: entry from agg prefix, thread-serial scan, apply + write -------
__global__ __launch_bounds__(TPB) void k_apply(
    const float4* __restrict__ x4,
    const float* __restrict__ kern,
    const float* __restrict__ state,
    const float2* __restrict__ agg,
    float* __restrict__ out,          // T outputs + 1 new_state
    int nblocks)
{
    __shared__ float rl[WAVES], rh[WAVES];     // for agg-prefix reduce
    __shared__ float wtl[WAVES], wth[WAVES];   // wave totals of thread aggs
    __shared__ float s_vb;

    const int t = threadIdx.x, lane = t & 63, w = t >> 6;
    const int b = blockIdx.x;
    const float k = kern[0];

    // ---- (A) block entry value: exclusive prefix over agg[0..b-1] ----
    {
        const int per = nblocks / TPB;   // 4
        float lo = -INFINITY, hi = INFINITY;
#pragma unroll
        for (int c = 0; c < per; ++c) {
            int j = t * per + c;
            if (j < b) {
                float2 ag = agg[j];
                lo = clampf(lo, ag.x, ag.y);
                hi = clampf(hi, ag.x, ag.y);
            }
        }
#pragma unroll
        for (int off = 1; off < 64; off <<= 1) {
            float plo = __shfl_down(lo, off);
            float phi_ = __shfl_down(hi, off);
            float nlo = clampf(lo, plo, phi_);
            float nhi = clampf(hi, plo, phi_);
            lo = nlo; hi = nhi;
        }
        if (lane == 0) { rl[w] = lo; rh[w] = hi; }
    }
    __syncthreads();
    if (t == 0) {
        float L = rl[0], H = rh[0];
#pragma unroll
        for (int i = 1; i < WAVES; ++i) {
            L = clampf(L, rl[i], rh[i]);
            H = clampf(H, rl[i], rh[i]);
        }
        s_vb = clampf(state[0], L, H);   // block entry VALUE
    }

    // ---- (B) load 32 contiguous elements, thread-serial aggregate ----
    const float4* p = x4 + (size_t)b * (ELEMS / 4) + (size_t)t * (PT / 4);
    float a[PT];
    float lo = -INFINITY, hi = INFINITY;
#pragma unroll
    for (int i = 0; i < PT / 4; ++i) {
        float4 v = p[i];
        a[4 * i + 0] = v.x * k; a[4 * i + 1] = v.y * k;
        a[4 * i + 2] = v.z * k; a[4 * i + 3] = v.w * k;
#pragma unroll
        for (int c = 0; c < 4; ++c) {
            float q = a[4 * i + c];
            lo = clampf(lo, q, q + 1.0f);
            hi = clampf(hi, q, q + 1.0f);
        }
    }

    // ---- (C) ONE wave inclusive scan on thread totals (prefix FIRST) ----
#pragma unroll
    for (int off = 1; off < 64; off <<= 1) {
        float plo = __shfl_up(lo, off);
        float phi_ = __shfl_up(hi, off);
        if (lane >= off) {
            float nlo = clampf(plo, lo, hi);
            float nhi = clampf(phi_, lo, hi);
            lo = nlo; hi = nhi;
        }
    }
    float elo = __shfl_up(lo, 1), ehi = __shfl_up(hi, 1);  // lane-exclusive pair
    if (lane == 0) { elo = -INFINITY; ehi = INFINITY; }
    if (lane == 63) { wtl[w] = lo; wth[w] = hi; }          // wave total
    __syncthreads();

    // ---- (D) thread entry VALUE: block entry -> earlier waves -> lane-excl
    float v = s_vb;
    for (int i = 0; i < w; ++i) v = clampf(v, wtl[i], wth[i]);
    v = clampf(v, elo, ehi);

    // ---- (E) serial apply + contiguous stores ----
    float4* o = (float4*)(out + (size_t)b * ELEMS + (size_t)t * PT);
#pragma unroll
    for (int i = 0; i < PT / 4; ++i) {
        float4 r;
        v = clampf(v, a[4 * i + 0], a[4 * i + 0] + 1.0f); r.x = v;
        v = clampf(v, a[4 * i + 1], a[4 * i + 1] + 1.0f); r.y = v;
        v = clampf(v, a[4 * i + 2], a[4 * i + 2] + 1.0f); r.z = v;
        v = clampf(v, a[4 * i + 3], a[4 * i + 3] + 1.0f); r.w = v;
        o[i] = r;
    }

    if (b == nblocks - 1 && t == TPB - 1)
        out[(size_t)nblocks * ELEMS] = v;    // new_state = last output
}

extern "C" void kernel_launch(void* const* d_in, const int* in_sizes, int n_in,
                              void* d_out, int out_size, void* d_ws, size_t ws_size,
                              hipStream_t stream) {
    const float4* x4   = (const float4*)d_in[0];   // [1,T]
    const float* state = (const float*)d_in[1];    // [1,1]
    const float* kern  = (const float*)d_in[2];    // [1,1]
    float* out = (float*)d_out;                    // T outputs + 1 new_state

    const size_t T = (size_t)in_sizes[0];
    const int nblocks = (int)(T / ELEMS);          // 1024 for T=2^23
    float2* agg = (float2*)d_ws;                   // fully written by K1 before K2 reads

    k_agg<<<nblocks, TPB, 0, stream>>>(x4, kern, agg);
    k_apply<<<nblocks, TPB, 0, stream>>>(x4, kern, state, agg, out, nblocks);
}

// Round 8
// 97.969 us; speedup vs baseline: 2.7709x; 1.0271x over previous
//
#include <hip/hip_runtime.h>
#include <math.h>

// out_i = clamp(out_{i-1}; a_i, a_i+1), a_i = x_i * k.  Clamp functions
// p -> min(max(p,lo),hi) compose associatively -> parallel scan.
//
// Deterministic 2-dispatch scan (proven absmax 0.0 in R5/R7).  R8 tuning:
//  - lane owns 8 CONTIGUOUS floats per segment (32B/lane stride: 16 cache
//    lines per load instr = 2x ideal, vs 64 lines/instr in R7's layout)
//  - 4 segments/block (halves ds_bpermute count vs R5's 8)
//  - serial in-register compose over the 8 lane-local elements

#define TPB 256
#define WAVES (TPB / 64)
#define SEGS 4
#define FPL 8                        // contiguous floats per lane per segment
#define SEG_ELEMS (TPB * FPL)        // 2048
#define ELEMS (SEGS * SEG_ELEMS)     // 8192 -> 1024 blocks @ T=2^23

__device__ __forceinline__ float clampf(float x, float lo, float hi) {
    return fminf(fmaxf(x, lo), hi);
}

// ---------------- K1: per-block composed clamp aggregate ----------------
__global__ __launch_bounds__(TPB) void k_agg(const float4* __restrict__ x4,
                                             const float* __restrict__ kern,
                                             float2* __restrict__ agg) {
    __shared__ float wl[SEGS][WAVES], wh[SEGS][WAVES];
    const int t = threadIdx.x, lane = t & 63, w = t >> 6;
    const int b = blockIdx.x;
    const float k = kern[0];
    const size_t base4 = (size_t)b * (ELEMS / 4);

#pragma unroll
    for (int s = 0; s < SEGS; ++s) {
        const size_t i4 = base4 + (size_t)s * (SEG_ELEMS / 4) + (size_t)t * 2;
        float4 v0 = x4[i4], v1 = x4[i4 + 1];
        float lo, hi, a;
        a = v0.x * k; lo = a; hi = a + 1.0f;
        a = v0.y * k; lo = clampf(lo, a, a + 1.0f); hi = clampf(hi, a, a + 1.0f);
        a = v0.z * k; lo = clampf(lo, a, a + 1.0f); hi = clampf(hi, a, a + 1.0f);
        a = v0.w * k; lo = clampf(lo, a, a + 1.0f); hi = clampf(hi, a, a + 1.0f);
        a = v1.x * k; lo = clampf(lo, a, a + 1.0f); hi = clampf(hi, a, a + 1.0f);
        a = v1.y * k; lo = clampf(lo, a, a + 1.0f); hi = clampf(hi, a, a + 1.0f);
        a = v1.z * k; lo = clampf(lo, a, a + 1.0f); hi = clampf(hi, a, a + 1.0f);
        a = v1.w * k; lo = clampf(lo, a, a + 1.0f); hi = clampf(hi, a, a + 1.0f);
        // ordered wave reduce: self (earlier) FIRST, lane+off (later) SECOND.
        // OOB shfl returns self; self-compose of a clamp pair is identity.
#pragma unroll
        for (int off = 1; off < 64; off <<= 1) {
            float plo = __shfl_down(lo, off);
            float phi_ = __shfl_down(hi, off);
            float nlo = clampf(lo, plo, phi_);
            float nhi = clampf(hi, plo, phi_);
            lo = nlo; hi = nhi;
        }
        if (lane == 0) { wl[s][w] = lo; wh[s][w] = hi; }
    }
    __syncthreads();
    if (t == 0) {
        float L = -INFINITY, H = INFINITY;
#pragma unroll
        for (int s = 0; s < SEGS; ++s)       // (s,w) lexicographic = element order
#pragma unroll
            for (int i = 0; i < WAVES; ++i) {
                L = clampf(L, wl[s][i], wh[s][i]);
                H = clampf(H, wl[s][i], wh[s][i]);
            }
        agg[b] = make_float2(L, H);
    }
}

// ------- K2: entry from agg prefix, per-segment scan, apply + write -------
__global__ __launch_bounds__(TPB) void k_apply(
    const float4* __restrict__ x4,
    const float* __restrict__ kern,
    const float* __restrict__ state,
    const float2* __restrict__ agg,
    float* __restrict__ out,          // T outputs + 1 new_state
    int nblocks)
{
    __shared__ float rl[WAVES], rh[WAVES];
    __shared__ float wtl[SEGS][WAVES], wth[SEGS][WAVES];
    __shared__ float s_vb;

    const int t = threadIdx.x, lane = t & 63, w = t >> 6;
    const int b = blockIdx.x;
    const float k = kern[0];
    const size_t base4 = (size_t)b * (ELEMS / 4);

    // ---- (A) block entry value: exclusive prefix over agg[0..b-1] ----
    {
        const int per = nblocks / TPB;   // 4
        float lo = -INFINITY, hi = INFINITY;
#pragma unroll
        for (int c = 0; c < per; ++c) {
            int j = t * per + c;
            if (j < b) {
                float2 ag = agg[j];
                lo = clampf(lo, ag.x, ag.y);
                hi = clampf(hi, ag.x, ag.y);
            }
        }
#pragma unroll
        for (int off = 1; off < 64; off <<= 1) {
            float plo = __shfl_down(lo, off);
            float phi_ = __shfl_down(hi, off);
            float nlo = clampf(lo, plo, phi_);
            float nhi = clampf(hi, plo, phi_);
            lo = nlo; hi = nhi;
        }
        if (lane == 0) { rl[w] = lo; rh[w] = hi; }
    }
    __syncthreads();
    if (t == 0) {
        float L = rl[0], H = rh[0];
#pragma unroll
        for (int i = 1; i < WAVES; ++i) {
            L = clampf(L, rl[i], rh[i]);
            H = clampf(H, rl[i], rh[i]);
        }
        s_vb = clampf(state[0], L, H);   // block entry VALUE
    }

    // ---- (B) per-segment: load 8 contiguous floats, lane pair, wave scan ----
    float a[SEGS][FPL];
    float eslo[SEGS], eshi[SEGS];   // compose(earlier waves, earlier lanes) per seg
    float Slo[SEGS], Shi[SEGS];     // segment totals (filled after barrier)

#pragma unroll
    for (int s = 0; s < SEGS; ++s) {
        const size_t i4 = base4 + (size_t)s * (SEG_ELEMS / 4) + (size_t)t * 2;
        float4 v0 = x4[i4], v1 = x4[i4 + 1];
        a[s][0] = v0.x * k; a[s][1] = v0.y * k; a[s][2] = v0.z * k; a[s][3] = v0.w * k;
        a[s][4] = v1.x * k; a[s][5] = v1.y * k; a[s][6] = v1.z * k; a[s][7] = v1.w * k;
        float lo = a[s][0], hi = a[s][0] + 1.0f;
#pragma unroll
        for (int c = 1; c < FPL; ++c) {
            lo = clampf(lo, a[s][c], a[s][c] + 1.0f);
            hi = clampf(hi, a[s][c], a[s][c] + 1.0f);
        }
        // wave inclusive scan on lane pairs (prefix FIRST, self SECOND)
#pragma unroll
        for (int off = 1; off < 64; off <<= 1) {
            float plo = __shfl_up(lo, off);
            float phi_ = __shfl_up(hi, off);
            if (lane >= off) {
                float nlo = clampf(plo, lo, hi);
                float nhi = clampf(phi_, lo, hi);
                lo = nlo; hi = nhi;
            }
        }
        float elo = __shfl_up(lo, 1), ehi = __shfl_up(hi, 1);
        if (lane == 0) { elo = -INFINITY; ehi = INFINITY; }
        eslo[s] = elo; eshi[s] = ehi;
        if (lane == 63) { wtl[s][w] = lo; wth[s][w] = hi; }
    }
    __syncthreads();

#pragma unroll
    for (int s = 0; s < SEGS; ++s) {
        float welo = -INFINITY, wehi = INFINITY;   // earlier waves in this segment
        for (int i = 0; i < w; ++i) {
            welo = clampf(welo, wtl[s][i], wth[s][i]);
            wehi = clampf(wehi, wtl[s][i], wth[s][i]);
        }
        float llo = eslo[s], lhi = eshi[s];
        eslo[s] = clampf(welo, llo, lhi);          // compose(waves-before, lanes-before)
        eshi[s] = clampf(wehi, llo, lhi);
        float stl = -INFINITY, sth = INFINITY;     // segment total
#pragma unroll
        for (int i = 0; i < WAVES; ++i) {
            stl = clampf(stl, wtl[s][i], wth[s][i]);
            sth = clampf(sth, wtl[s][i], wth[s][i]);
        }
        Slo[s] = stl; Shi[s] = sth;
    }

    // ---- (C) thread the value, apply, coalesced-ish stores ----
    __syncthreads();                 // s_vb visible
    float p = s_vb;
    float wv = p;
#pragma unroll
    for (int s = 0; s < SEGS; ++s) {
        wv = clampf(p, eslo[s], eshi[s]);          // this thread's entry in segment
        float4 r0, r1;
        wv = clampf(wv, a[s][0], a[s][0] + 1.0f); r0.x = wv;
        wv = clampf(wv, a[s][1], a[s][1] + 1.0f); r0.y = wv;
        wv = clampf(wv, a[s][2], a[s][2] + 1.0f); r0.z = wv;
        wv = clampf(wv, a[s][3], a[s][3] + 1.0f); r0.w = wv;
        wv = clampf(wv, a[s][4], a[s][4] + 1.0f); r1.x = wv;
        wv = clampf(wv, a[s][5], a[s][5] + 1.0f); r1.y = wv;
        wv = clampf(wv, a[s][6], a[s][6] + 1.0f); r1.z = wv;
        wv = clampf(wv, a[s][7], a[s][7] + 1.0f); r1.w = wv;
        float4* o = (float4*)(out + (size_t)b * ELEMS + (size_t)s * SEG_ELEMS) + (size_t)t * 2;
        o[0] = r0; o[1] = r1;
        p = clampf(p, Slo[s], Shi[s]);             // advance past segment
    }

    if (b == nblocks - 1 && t == TPB - 1)
        out[(size_t)nblocks * ELEMS] = wv;         // new_state = last output
}

extern "C" void kernel_launch(void* const* d_in, const int* in_sizes, int n_in,
                              void* d_out, int out_size, void* d_ws, size_t ws_size,
                              hipStream_t stream) {
    const float4* x4   = (const float4*)d_in[0];   // [1,T]
    const float* state = (const float*)d_in[1];    // [1,1]
    const float* kern  = (const float*)d_in[2];    // [1,1]
    float* out = (float*)d_out;                    // T outputs + 1 new_state

    const size_t T = (size_t)in_sizes[0];
    const int nblocks = (int)(T / ELEMS);          // 1024 for T=2^23
    float2* agg = (float2*)d_ws;                   // fully written by K1 before K2 reads

    k_agg<<<nblocks, TPB, 0, stream>>>(x4, kern, agg);
    k_apply<<<nblocks, TPB, 0, stream>>>(x4, kern, state, agg, out, nblocks);
}